// Round 3
// baseline (574.714 us; speedup 1.0000x reference)
//
#include <hip/hip_runtime.h>
#include <hip/hip_bf16.h>
#include <math.h>

// Problem constants (from the reference file; RECORD_LEN is a module constant).
#define C_DIM 256
#define W_DIM 64
#define H_DIM 192
#define WH (W_DIM * H_DIM)          // 12288 spatial positions
#define NGROUPS 8

// Block decomposition: 256 threads = 64 spatial positions x 4 channel-chunks.
// 4x more blocks than one-thread-per-n => 24 waves/CU (was 6) for latency hiding.
#define NL 64                        // n positions per block
#define NCHUNK 4                     // channel chunks per block
#define CCHUNK (C_DIM / NCHUNK)      // 64 channels per chunk
#define BLOCKS_PER_GROUP (WH / NL)   // 192
#define MAX_NTRI 15                  // L=5 triangle
#define MAX_L 5

// LDS layout: [0, NCHUNK*MAX_NTRI*NL) partial grams; then MAX_L*NL for p0.
#define LDS_P0_OFF (NCHUNK * MAX_NTRI * NL)
#define LDS_FLOATS (LDS_P0_OFF + MAX_L * NL)

template <int L, bool WRITE_ATTN>
__device__ __forceinline__ void att_group_body(
    const float* __restrict__ xg,   // group base: x + off*C*WH
    float* __restrict__ out,        // out0 + g*C*WH  (C, WH)
    float* __restrict__ attn_out,   // (L, L, WH) or nullptr
    float* lds, int n0)
{
    constexpr int NTRI = L * (L + 1) / 2;
    const int tid = threadIdx.x;
    const int n_local = tid & (NL - 1);
    const int chunk = tid >> 6;          // wave-uniform (wave == chunk)
    const int n = n0 + n_local;
    const int c0 = chunk * CCHUNK;

    // ---- Pass 1: partial gram over this thread's 64 channels ----
    float s[NTRI];
#pragma unroll
    for (int i = 0; i < NTRI; ++i) s[i] = 0.0f;

#pragma unroll 2
    for (int cc = 0; cc < CCHUNK; ++cc) {
        const int c = c0 + cc;
        float v[L];
#pragma unroll
        for (int l = 0; l < L; ++l)
            v[l] = xg[((size_t)(l * C_DIM + c)) * WH + n];
        int idx = 0;
#pragma unroll
        for (int l = 0; l < L; ++l)
#pragma unroll
            for (int m = l; m < L; ++m)
                s[idx++] += v[l] * v[m];
    }

    // partials -> LDS: [(chunk*NTRI + t)*NL + n_local], lanes stride-1 (no conflict)
#pragma unroll
    for (int t = 0; t < NTRI; ++t)
        lds[(chunk * NTRI + t) * NL + n_local] = s[t];
    __syncthreads();

    const float scale = 0.0625f;   // 1/sqrt(256)

    // ---- Reduce + softmax: threads 0..63 (one wave), one n each ----
    if (tid < NL) {
        float tot[NTRI];
#pragma unroll
        for (int t = 0; t < NTRI; ++t) {
            float a = 0.0f;
#pragma unroll
            for (int k = 0; k < NCHUNK; ++k)
                a += lds[(k * NTRI + t) * NL + tid];
            tot[t] = a * scale;
        }

        // row 0 of the gram == first L triangle entries
        float p0[L];
        float mx = -INFINITY;
#pragma unroll
        for (int m = 0; m < L; ++m) mx = fmaxf(mx, tot[m]);
        float sum = 0.0f;
#pragma unroll
        for (int m = 0; m < L; ++m) {
            p0[m] = __expf(tot[m] - mx);
            sum += p0[m];
        }
        const float inv = 1.0f / sum;
#pragma unroll
        for (int m = 0; m < L; ++m)
            lds[LDS_P0_OFF + m * NL + tid] = p0[m] * inv;

        if constexpr (WRITE_ATTN) {
            // full LxL softmax map, layout [l][m][n]
            float g[L][L];
            int idx = 0;
#pragma unroll
            for (int l = 0; l < L; ++l)
#pragma unroll
                for (int m = l; m < L; ++m) {
                    g[l][m] = tot[idx];
                    g[m][l] = tot[idx];
                    ++idx;
                }
#pragma unroll
            for (int l = 0; l < L; ++l) {
                float mx2 = -INFINITY;
#pragma unroll
                for (int m = 0; m < L; ++m) mx2 = fmaxf(mx2, g[l][m]);
                float e[L];
                float sm = 0.0f;
#pragma unroll
                for (int m = 0; m < L; ++m) {
                    e[m] = __expf(g[l][m] - mx2);
                    sm += e[m];
                }
                const float iv = 1.0f / sm;
#pragma unroll
                for (int m = 0; m < L; ++m)
                    attn_out[((size_t)(l * L + m)) * WH + n0 + tid] = e[m] * iv;
            }
        }
    }
    __syncthreads();

    // ---- Pass 2: context, each thread emits its 64 channels ----
    float p[L];
#pragma unroll
    for (int m = 0; m < L; ++m)
        p[m] = lds[LDS_P0_OFF + m * NL + n_local];

#pragma unroll 4
    for (int cc = 0; cc < CCHUNK; ++cc) {
        const int c = c0 + cc;
        float acc = 0.0f;
#pragma unroll
        for (int m = 0; m < L; ++m)
            acc += p[m] * xg[((size_t)(m * C_DIM + c)) * WH + n];
        out[(size_t)c * WH + n] = acc;
    }
}

__global__ __launch_bounds__(256, 6) void att_fused_kernel(
    const float* __restrict__ x,
    float* __restrict__ out0,
    float* __restrict__ attn)
{
    __shared__ float lds[LDS_FLOATS];   // 16.6 KB

    const int b = blockIdx.x;
    const int g = b / BLOCKS_PER_GROUP;            // block-uniform
    const int bn = b - g * BLOCKS_PER_GROUP;
    const int n0 = bn * NL;

    const int offs[NGROUPS] = {0, 5, 8, 12, 14, 19, 22, 26};
    const int lens[NGROUPS] = {5, 3, 4, 2, 5, 3, 4, 2};

    const float* xg = x + (size_t)offs[g] * C_DIM * WH;
    float* og = out0 + (size_t)g * C_DIM * WH;

    switch (lens[g]) {   // block-uniform branch -> no divergence
        case 5: att_group_body<5, false>(xg, og, nullptr, lds, n0); break;
        case 4: att_group_body<4, false>(xg, og, nullptr, lds, n0); break;
        case 3: att_group_body<3, false>(xg, og, nullptr, lds, n0); break;
        case 2:
            if (g == NGROUPS - 1)
                att_group_body<2, true>(xg, og, attn, lds, n0);
            else
                att_group_body<2, false>(xg, og, nullptr, lds, n0);
            break;
    }
}

extern "C" void kernel_launch(void* const* d_in, const int* in_sizes, int n_in,
                              void* d_out, int out_size, void* d_ws, size_t ws_size,
                              hipStream_t stream) {
    const float* x = (const float*)d_in[0];
    float* out0 = (float*)d_out;                        // (8, C, W, H)
    float* attn = out0 + (size_t)NGROUPS * C_DIM * WH;  // (2, 2, W, H), last group

    const dim3 grid(NGROUPS * BLOCKS_PER_GROUP);   // 1536
    const dim3 block(256);
    att_fused_kernel<<<grid, block, 0, stream>>>(x, out0, attn);
}